// Round 1
// baseline (7303.044 us; speedup 1.0000x reference)
//
#include <hip/hip_runtime.h>
#include <math.h>

namespace {

constexpr int H  = 64;    // hidden
constexpr int G4 = 256;   // 4*H gates
constexpr int T  = 256;   // seq len
constexpr int GB = 4;     // batch elems per block
constexpr int MAT_F = 16384;  // floats per packed 256x64 matrix

__device__ __forceinline__ float sgm(float x) { return 1.0f / (1.0f + expf(-x)); }

// Pack each [256 x 64] weight matrix (row-major, possibly strided/offset) into
// k-panel layout P[k/4][j][k%4] so that lane j reads float4 at (panel*4096 + j*16)B
// -> fully coalesced 1KB wave loads in the main kernel.
__global__ void pack_kernel(const float* __restrict__ eWhh0,
                            const float* __restrict__ eWih1, const float* __restrict__ eWhh1,
                            const float* __restrict__ eWih2, const float* __restrict__ eWhh2,
                            const float* __restrict__ dWih0, const float* __restrict__ dWhh0,
                            const float* __restrict__ dWih1, const float* __restrict__ dWhh1,
                            const float* __restrict__ dWih2, const float* __restrict__ dWhh2,
                            float* __restrict__ ws) {
  const int m = blockIdx.x >> 6;
  const int i = ((blockIdx.x & 63) << 8) | threadIdx.x;  // 0..16383
  const float* src;
  int ld = 64, off = 0;
  switch (m) {
    case 0: src = eWhh0; break;
    case 1: src = eWih1; break;
    case 2: src = eWhh1; break;
    case 3: src = eWih2; break;
    case 4: src = eWhh2; break;
    case 5: src = dWih0; ld = 65; off = 1; break;  // y_prev part: cols 1..64
    case 6: src = dWhh0; break;
    case 7: src = dWih1; break;
    case 8: src = dWhh1; break;
    case 9: src = dWih2; break;
    default: src = dWhh2; break;
  }
  const int kk = i >> 10, rem = i & 1023, j = rem >> 2, r = rem & 3;
  ws[m * MAT_F + i] = src[j * ld + off + kk * 4 + r];
}

// acc[g] += sum_k W[j][k] * hs[g][k], weights in packed k-panel layout.
__device__ __forceinline__ void accum_mat(const float4* __restrict__ wp,
                                          const float (*hs)[H], int j, float* acc) {
#pragma unroll
  for (int kk = 0; kk < 16; ++kk) {
    const float4 w = wp[kk * 256 + j];
#pragma unroll
    for (int g = 0; g < GB; ++g) {
      const float4 hv = *(const float4*)&hs[g][kk * 4];
      acc[g] += w.x * hv.x + w.y * hv.y + w.z * hv.z + w.w * hv.w;
    }
  }
}

// z -> gates -> (h,c) update. Thread j wrote z for gate j (all GB batch);
// after barrier, thread (g2,u) combines gates u, u+64, u+128, u+192.
__device__ __forceinline__ float gate_update(float* zb, float (*h)[GB][H], float (*c)[GB][H],
                                             int l, int g2, int u, const float* acc, int j) {
#pragma unroll
  for (int g = 0; g < GB; ++g) zb[g * G4 + j] = acc[g];
  __syncthreads();
  const float zi = zb[g2 * G4 + u];
  const float zf = zb[g2 * G4 + u + 64];
  const float zg = zb[g2 * G4 + u + 128];
  const float zo = zb[g2 * G4 + u + 192];
  const float ii = sgm(zi), ff = sgm(zf), gg = tanhf(zg), oo = sgm(zo);
  const float cn = ff * c[l][g2][u] + ii * gg;
  const float hn = oo * tanhf(cn);
  c[l][g2][u] = cn;
  h[l][g2][u] = hn;
  return hn;
}

__global__ __launch_bounds__(256) void seq2seq_kernel(
    const float* __restrict__ enc_x, const float* __restrict__ dec_x,
    const float* __restrict__ eWih0, const float* __restrict__ eb0,
    const float* __restrict__ eb1, const float* __restrict__ eb2,
    const float* __restrict__ dWih0, const float* __restrict__ db0,
    const float* __restrict__ db1, const float* __restrict__ db2,
    const float* __restrict__ fcW, const float* __restrict__ fcb,
    const float* __restrict__ wsp, float* __restrict__ out) {
  __shared__ float h[3][GB][H];
  __shared__ float c[3][GB][H];
  __shared__ float zb[GB][G4];
  __shared__ float yprev[GB][H];
  __shared__ float xs[2][GB][T];

  const int tid = threadIdx.x;
  const int b0 = blockIdx.x * GB;

  // stage x (contiguous, coalesced) and zero state
  for (int i = tid; i < GB * T; i += 256) {
    ((float*)xs[0])[i] = enc_x[b0 * T + i];
    ((float*)xs[1])[i] = dec_x[b0 * T + i];
  }
  for (int i = tid; i < 3 * GB * H; i += 256) {
    ((float*)h)[i] = 0.f;
    ((float*)c)[i] = 0.f;
  }
  for (int i = tid; i < GB * H; i += 256) ((float*)yprev)[i] = 0.f;

  const int j = tid;
  const float be0 = eb0[j], be1 = eb1[j], be2 = eb2[j];
  const float bd0 = db0[j], bd1 = db1[j], bd2 = db2[j];
  const float wx0 = eWih0[j];        // enc layer0 input weight (I=1)
  const float wxd0 = dWih0[j * 65];  // dec layer0 x-column (col 0 of concat)
  const int g2 = tid >> 6, u = tid & 63;
  const float fcw = fcW[u];
  const float fcbv = fcb[0];

  const float4* mats = (const float4*)wsp;  // each packed mat = 4096 float4
  const float4* p_eWhh0 = mats + 0 * 4096;
  const float4* p_eWih1 = mats + 1 * 4096;
  const float4* p_eWhh1 = mats + 2 * 4096;
  const float4* p_eWih2 = mats + 3 * 4096;
  const float4* p_eWhh2 = mats + 4 * 4096;
  const float4* p_dWih0y = mats + 5 * 4096;
  const float4* p_dWhh0 = mats + 6 * 4096;
  const float4* p_dWih1 = mats + 7 * 4096;
  const float4* p_dWhh1 = mats + 8 * 4096;
  const float4* p_dWih2 = mats + 9 * 4096;
  const float4* p_dWhh2 = mats + 10 * 4096;

  __syncthreads();

  // ---------------- Encoder ----------------
  for (int t = 0; t < T; ++t) {
    float acc[GB];
    // layer 0: z = b + x*Wih0 + Whh0 h0
#pragma unroll
    for (int g = 0; g < GB; ++g) acc[g] = be0 + xs[0][g][t] * wx0;
    accum_mat(p_eWhh0, h[0], j, acc);
    gate_update(&zb[0][0], h, c, 0, g2, u, acc, j);
    __syncthreads();
    // layer 1
#pragma unroll
    for (int g = 0; g < GB; ++g) acc[g] = be1;
    accum_mat(p_eWih1, h[0], j, acc);
    accum_mat(p_eWhh1, h[1], j, acc);
    gate_update(&zb[0][0], h, c, 1, g2, u, acc, j);
    __syncthreads();
    // layer 2
#pragma unroll
    for (int g = 0; g < GB; ++g) acc[g] = be2;
    accum_mat(p_eWih2, h[1], j, acc);
    accum_mat(p_eWhh2, h[2], j, acc);
    gate_update(&zb[0][0], h, c, 2, g2, u, acc, j);
    __syncthreads();
  }

  // ---------------- Decoder ----------------
  // (h,c) carry over from encoder final state; yprev starts at zeros.
  for (int t = 0; t < T; ++t) {
    float acc[GB];
    // layer 0: input = concat(x, y_prev)
#pragma unroll
    for (int g = 0; g < GB; ++g) acc[g] = bd0 + xs[1][g][t] * wxd0;
    accum_mat(p_dWih0y, yprev, j, acc);
    accum_mat(p_dWhh0, h[0], j, acc);
    gate_update(&zb[0][0], h, c, 0, g2, u, acc, j);
    __syncthreads();
    // layer 1
#pragma unroll
    for (int g = 0; g < GB; ++g) acc[g] = bd1;
    accum_mat(p_dWih1, h[0], j, acc);
    accum_mat(p_dWhh1, h[1], j, acc);
    gate_update(&zb[0][0], h, c, 1, g2, u, acc, j);
    __syncthreads();
    // layer 2 + fc
#pragma unroll
    for (int g = 0; g < GB; ++g) acc[g] = bd2;
    accum_mat(p_dWih2, h[1], j, acc);
    accum_mat(p_dWhh2, h[2], j, acc);
    const float hn = gate_update(&zb[0][0], h, c, 2, g2, u, acc, j);
    // fc: pred[g2] = dot(fcW, h2_new[g2]) + fcb  (wave g2 owns batch elem g2)
    float p = hn * fcw;
#pragma unroll
    for (int o = 32; o > 0; o >>= 1) p += __shfl_down(p, o, 64);
    if (u == 0) out[(b0 + g2) * T + t] = p + fcbv;
    yprev[g2][u] = hn;  // y_prev for t+1
    __syncthreads();
  }
}

}  // namespace

extern "C" void kernel_launch(void* const* d_in, const int* in_sizes, int n_in,
                              void* d_out, int out_size, void* d_ws, size_t ws_size,
                              hipStream_t stream) {
  const float* enc_x = (const float*)d_in[0];
  const float* dec_x = (const float*)d_in[1];
  const float* eWih0 = (const float*)d_in[2];
  const float* eWhh0 = (const float*)d_in[3];
  const float* eb0   = (const float*)d_in[4];
  const float* eWih1 = (const float*)d_in[5];
  const float* eWhh1 = (const float*)d_in[6];
  const float* eb1   = (const float*)d_in[7];
  const float* eWih2 = (const float*)d_in[8];
  const float* eWhh2 = (const float*)d_in[9];
  const float* eb2   = (const float*)d_in[10];
  const float* dWih0 = (const float*)d_in[11];
  const float* dWhh0 = (const float*)d_in[12];
  const float* db0   = (const float*)d_in[13];
  const float* dWih1 = (const float*)d_in[14];
  const float* dWhh1 = (const float*)d_in[15];
  const float* db1   = (const float*)d_in[16];
  const float* dWih2 = (const float*)d_in[17];
  const float* dWhh2 = (const float*)d_in[18];
  const float* db2   = (const float*)d_in[19];
  const float* fcW   = (const float*)d_in[20];
  const float* fcb   = (const float*)d_in[21];
  float* ws  = (float*)d_ws;
  float* out = (float*)d_out;

  pack_kernel<<<dim3(11 * 64), dim3(256), 0, stream>>>(
      eWhh0, eWih1, eWhh1, eWih2, eWhh2, dWih0, dWhh0, dWih1, dWhh1, dWih2, dWhh2, ws);
  seq2seq_kernel<<<dim3(256), dim3(256), 0, stream>>>(
      enc_x, dec_x, eWih0, eb0, eb1, eb2, dWih0, db0, db1, db2, fcW, fcb, ws, out);
}

// Round 2
// 2225.039 us; speedup vs baseline: 3.2822x; 3.2822x over previous
//
#include <hip/hip_runtime.h>

namespace {

constexpr int H  = 64;    // hidden
constexpr int G4 = 256;   // 4*H gates
constexpr int T  = 256;   // seq len
constexpr int GB = 4;     // batch elems per block

__device__ __forceinline__ float frcp(float x) { return __builtin_amdgcn_rcpf(x); }
__device__ __forceinline__ float sgm(float x) { return frcp(1.f + __expf(-x)); }
__device__ __forceinline__ float ftanh(float x) {
  const float e = __expf(-2.f * x);
  return (1.f - e) * frcp(1.f + e);
}

// Load this thread's 32-float k-slice of row j from a row-major [256 x 64] matrix.
__device__ __forceinline__ void loadmat(float4 (&w)[8], const float* __restrict__ W,
                                        int j, int q) {
#pragma unroll
  for (int r = 0; r < 8; ++r)
    w[r] = *(const float4*)(W + j * 64 + q * 32 + r * 4);
}

// Same but from the y-part (cols 1..64) of the dec L0 [256 x 65] matrix (unaligned).
__device__ __forceinline__ void loadmat_y(float4 (&w)[8], const float* __restrict__ W,
                                          int j, int q) {
#pragma unroll
  for (int r = 0; r < 8; ++r) {
    const float* p = W + j * 65 + 1 + q * 32 + r * 4;
    w[r] = make_float4(p[0], p[1], p[2], p[3]);
  }
}

// acc[g] += W[j][32q:32q+32] . hs[g][32q:32q+32]   (weights in regs, h broadcast from LDS)
__device__ __forceinline__ void accum(const float4 (&w)[8], const float (*hs)[H], int q,
                                      float (&acc)[GB]) {
#pragma unroll
  for (int g = 0; g < GB; ++g) {
    const float4* hp = (const float4*)(&hs[g][q * 32]);
#pragma unroll
    for (int r = 0; r < 8; ++r) {
      const float4 hv = hp[r];
      acc[g] += w[r].x * hv.x + w[r].y * hv.y + w[r].z * hv.z + w[r].w * hv.w;
    }
  }
}

__global__ __launch_bounds__(512, 2) void seq2seq_kernel(
    const float* __restrict__ enc_x, const float* __restrict__ dec_x,
    const float* __restrict__ eWih0, const float* __restrict__ eWhh0,
    const float* __restrict__ eb0,
    const float* __restrict__ eWih1, const float* __restrict__ eWhh1,
    const float* __restrict__ eb1,
    const float* __restrict__ eWih2, const float* __restrict__ eWhh2,
    const float* __restrict__ eb2,
    const float* __restrict__ dWih0, const float* __restrict__ dWhh0,
    const float* __restrict__ db0,
    const float* __restrict__ dWih1, const float* __restrict__ dWhh1,
    const float* __restrict__ db1,
    const float* __restrict__ dWih2, const float* __restrict__ dWhh2,
    const float* __restrict__ db2,
    const float* __restrict__ fcW, const float* __restrict__ fcb,
    float* __restrict__ out) {
  __shared__ float h[3][GB][H];      // 3 KB  shared hidden state
  __shared__ float yprev[GB][H];     // 1 KB  decoder feedback (y_{t-1})
  __shared__ float zp[2][GB][G4];    // 8 KB  z partial sums (per k-half)
  __shared__ float xs[2][GB][T];     // 8 KB  staged enc_x / dec_x
  __shared__ float bias[6][G4];      // 6 KB

  const int tid = threadIdx.x;
  const int j = tid & 255;   // gate row
  const int q = tid >> 8;    // k-half (0: k<32, 1: k>=32)
  const int g2 = tid >> 6, u = tid & 63;  // update-phase mapping (tid<256)
  const int b0 = blockIdx.x * GB;

  // ---- stage x, biases; zero state ----
  for (int i = tid; i < GB * T; i += 512) {
    ((float*)xs[0])[i] = enc_x[b0 * T + i];
    ((float*)xs[1])[i] = dec_x[b0 * T + i];
  }
  if (tid < 256) {
    bias[0][tid] = eb0[tid]; bias[1][tid] = eb1[tid]; bias[2][tid] = eb2[tid];
    bias[3][tid] = db0[tid]; bias[4][tid] = db1[tid]; bias[5][tid] = db2[tid];
  }
  for (int i = tid; i < 3 * GB * H; i += 512) ((float*)h)[i] = 0.f;
  for (int i = tid; i < GB * H; i += 512) ((float*)yprev)[i] = 0.f;

  float cr0 = 0.f, cr1 = 0.f, cr2 = 0.f;           // cell state (update threads)
  const float fcw = fcW[u];
  const float fcbv = fcb[0];

  // ---- encoder weights -> registers (192 VGPR for 6 mats; enc uses 5) ----
  float4 w[6][8];
  loadmat(w[0], eWhh0, j, q);
  loadmat(w[1], eWih1, j, q);
  loadmat(w[2], eWhh1, j, q);
  loadmat(w[3], eWih2, j, q);
  loadmat(w[4], eWhh2, j, q);
  float xw = (q == 0) ? eWih0[j] : 0.f;   // I=1 input column

  __syncthreads();

// z-partials -> gates -> (h,c) update for layer L with bias row BROW.
#define ZUPD(L, BROW, EXTRA)                                                     \
  {                                                                              \
    _Pragma("unroll") for (int g = 0; g < GB; ++g) zp[q][g][j] = acc[g];         \
    __syncthreads();                                                             \
    if (tid < 256) {                                                             \
      const float zi = bias[BROW][u]       + zp[0][g2][u]       + zp[1][g2][u];  \
      const float zf = bias[BROW][u + 64]  + zp[0][g2][u + 64]  + zp[1][g2][u + 64];  \
      const float zg = bias[BROW][u + 128] + zp[0][g2][u + 128] + zp[1][g2][u + 128]; \
      const float zo = bias[BROW][u + 192] + zp[0][g2][u + 192] + zp[1][g2][u + 192]; \
      const float ii = sgm(zi), ff = sgm(zf), gg = ftanh(zg), oo = sgm(zo);      \
      const float cn = ff * cr##L + ii * gg;                                     \
      cr##L = cn;                                                                \
      const float hn = oo * ftanh(cn);                                           \
      h[L][g2][u] = hn;                                                          \
      EXTRA                                                                      \
    }                                                                            \
    __syncthreads();                                                             \
  }

  // ---------------- Encoder ----------------
  for (int t = 0; t < T; ++t) {
    float acc[GB];
#pragma unroll
    for (int g = 0; g < GB; ++g) acc[g] = xs[0][g][t] * xw;
    accum(w[0], h[0], q, acc);
    ZUPD(0, 0, )
#pragma unroll
    for (int g = 0; g < GB; ++g) acc[g] = 0.f;
    accum(w[1], h[0], q, acc);
    accum(w[2], h[1], q, acc);
    ZUPD(1, 1, )
#pragma unroll
    for (int g = 0; g < GB; ++g) acc[g] = 0.f;
    accum(w[3], h[1], q, acc);
    accum(w[4], h[2], q, acc);
    ZUPD(2, 2, )
  }

  // ---- decoder weights -> registers (regs are private; no barrier needed) ----
  loadmat_y(w[0], dWih0, j, q);   // y_prev columns of [256 x 65]
  loadmat(w[1], dWhh0, j, q);
  loadmat(w[2], dWih1, j, q);
  loadmat(w[3], dWhh1, j, q);
  loadmat(w[4], dWih2, j, q);
  loadmat(w[5], dWhh2, j, q);
  xw = (q == 0) ? dWih0[j * 65] : 0.f;   // x column of concat(x, y_prev)

  // ---------------- Decoder ----------------
  for (int t = 0; t < T; ++t) {
    float acc[GB];
#pragma unroll
    for (int g = 0; g < GB; ++g) acc[g] = xs[1][g][t] * xw;
    accum(w[0], yprev, q, acc);
    accum(w[1], h[0], q, acc);
    ZUPD(0, 3, )
#pragma unroll
    for (int g = 0; g < GB; ++g) acc[g] = 0.f;
    accum(w[2], h[0], q, acc);
    accum(w[3], h[1], q, acc);
    ZUPD(1, 4, )
#pragma unroll
    for (int g = 0; g < GB; ++g) acc[g] = 0.f;
    accum(w[4], h[1], q, acc);
    accum(w[5], h[2], q, acc);
    ZUPD(2, 5, {
      yprev[g2][u] = hn;
      float p = hn * fcw;
      _Pragma("unroll") for (int o = 32; o > 0; o >>= 1) p += __shfl_down(p, o, 64);
      if (u == 0) out[(b0 + g2) * T + t] = p + fcbv;
    })
  }
#undef ZUPD
}

}  // namespace

extern "C" void kernel_launch(void* const* d_in, const int* in_sizes, int n_in,
                              void* d_out, int out_size, void* d_ws, size_t ws_size,
                              hipStream_t stream) {
  const float* enc_x = (const float*)d_in[0];
  const float* dec_x = (const float*)d_in[1];
  const float* eWih0 = (const float*)d_in[2];
  const float* eWhh0 = (const float*)d_in[3];
  const float* eb0   = (const float*)d_in[4];
  const float* eWih1 = (const float*)d_in[5];
  const float* eWhh1 = (const float*)d_in[6];
  const float* eb1   = (const float*)d_in[7];
  const float* eWih2 = (const float*)d_in[8];
  const float* eWhh2 = (const float*)d_in[9];
  const float* eb2   = (const float*)d_in[10];
  const float* dWih0 = (const float*)d_in[11];
  const float* dWhh0 = (const float*)d_in[12];
  const float* db0   = (const float*)d_in[13];
  const float* dWih1 = (const float*)d_in[14];
  const float* dWhh1 = (const float*)d_in[15];
  const float* db1   = (const float*)d_in[16];
  const float* dWih2 = (const float*)d_in[17];
  const float* dWhh2 = (const float*)d_in[18];
  const float* db2   = (const float*)d_in[19];
  const float* fcW   = (const float*)d_in[20];
  const float* fcb   = (const float*)d_in[21];
  float* out = (float*)d_out;

  seq2seq_kernel<<<dim3(256), dim3(512), 0, stream>>>(
      enc_x, dec_x, eWih0, eWhh0, eb0, eWih1, eWhh1, eb1, eWih2, eWhh2, eb2,
      dWih0, dWhh0, db0, dWih1, dWhh1, db1, dWih2, dWhh2, db2, fcW, fcb, out);
}